// Round 6
// baseline (32.705 us; speedup 1.0000x reference)
//
#include <hip/hip_runtime.h>

// Problem constants (fixed shapes from setup_inputs)
#define B 8
#define S 4096
#define H 1152
#define OUT 256
#define KP 4            // pooling window k = sqrt(S/OUT) = 4
#define CAP 16          // per-segment source rows (k*k = 16)
#define H4 (H / 4)      // 288 float4 per output row
#define NT 576          // threads per block = 2 tokens * H4
#define TPB 8           // tokens per block
#define NI4 (S / 2)     // int4 position-pair entries per batch

typedef float f32x4 __attribute__((ext_vector_type(4)));

// Fully fused: one block = 8 output tokens. Scan batch positions once
// (32 KB, L2-resident), build 8 segment lists in LDS, then 4 gather
// iterations (2 tokens each, one float4 per thread). Fast path: all lists
// full -> branchless, fully unrolled, nontemporal streaming loads/stores.
__global__ __launch_bounds__(NT) void fused_pool_kernel(
    const float* __restrict__ x, const float* __restrict__ bias,
    const float* __restrict__ scale, const int* __restrict__ pos,
    float* __restrict__ out) {
    const int blk = blockIdx.x;         // over B*OUT/TPB = 256
    const int tid = threadIdx.x;
    const int b   = blk >> 5;           // 32 blocks per batch
    const int seg_base = (blk * TPB) & 255;

    __shared__ int s_max;
    __shared__ int s_cnt[TPB];
    __shared__ int s_lst[TPB][CAP];

    if (tid == 0) s_max = 0;
    if (tid < TPB) s_cnt[tid] = 0;

    // Pass 1: load this batch's positions (int4 = 2 coords, coalesced).
    int px[8], py[8];
    int mymax = 0;
    #pragma unroll
    for (int j = 0; j < 4; ++j) {
        const int i4 = tid + j * NT;
        if (i4 < NI4) {
            const int4 p = reinterpret_cast<const int4*>(pos)[b * NI4 + i4];
            px[2 * j] = p.x;     py[2 * j] = p.y;
            px[2 * j + 1] = p.z; py[2 * j + 1] = p.w;
            mymax = mymax > p.x ? mymax : p.x;
            mymax = mymax > p.z ? mymax : p.z;
        } else {
            px[2 * j] = -1; py[2 * j] = 0;
            px[2 * j + 1] = -1; py[2 * j + 1] = 0;
        }
    }
    #pragma unroll
    for (int off = 32; off > 0; off >>= 1) {
        const int o = __shfl_down(mymax, off, 64);
        mymax = mymax > o ? mymax : o;
    }
    __syncthreads();                    // s_max/s_cnt init visible
    if ((tid & 63) == 0) atomicMax(&s_max, mymax);
    __syncthreads();
    const int mxk = (s_max + 1) / KP;

    // Pass 2: match positions against this block's 8 segments -> LDS lists.
    #pragma unroll
    for (int j = 0; j < 8; ++j) {
        if (px[j] >= 0) {
            const int seg = px[j] / KP + mxk * (py[j] / KP);
            const unsigned m = (unsigned)(seg - seg_base);
            if (m < (unsigned)TPB) {
                const int slot = atomicAdd(&s_cnt[m], 1);
                if (slot < CAP)
                    s_lst[m][slot] = 2 * (tid + (j >> 1) * NT) + (j & 1);
            }
        }
    }
    __syncthreads();

    // Gather + pool + affine: 4 iterations, one float4 per thread each.
    const int k  = tid >= H4 ? 1 : 0;
    const int h4 = tid - k * H4;
    const float* xp = x + (size_t)b * S * H + (size_t)h4 * 4;
    const float mul = sqrtf((float)H) * (1.0f / (KP * KP));
    const f32x4 bs = *reinterpret_cast<const f32x4*>(bias + h4 * 4);
    const f32x4 sc = *reinterpret_cast<const f32x4*>(scale + h4 * 4);
    float* op = out + (size_t)blk * TPB * H + (size_t)h4 * 4;

    // Wave-uniform: are all 8 lists exactly full? (canonical 4x4 pooling)
    bool fast = true;
    #pragma unroll
    for (int m = 0; m < TPB; ++m) fast = fast && (s_cnt[m] == CAP);

    if (fast) {
        // Branchless, fully unrolled: compiler can pipeline loads across
        // token-pair iterations (no control flow between them).
        #pragma unroll
        for (int p = 0; p < TPB / 2; ++p) {
            const int m = 2 * p + k;
            f32x4 acc = {0.f, 0.f, 0.f, 0.f};
            #pragma unroll
            for (int i = 0; i < CAP; ++i) {
                const f32x4 v = __builtin_nontemporal_load(
                    reinterpret_cast<const f32x4*>(xp + (size_t)s_lst[m][i] * H));
                acc += v;
            }
            const f32x4 r = (acc * mul - bs) * sc;
            __builtin_nontemporal_store(
                r, reinterpret_cast<f32x4*>(op + (size_t)m * H));
        }
    } else {
        for (int p = 0; p < TPB / 2; ++p) {
            const int m = 2 * p + k;
            int cnt = s_cnt[m];
            if (cnt > CAP) cnt = CAP;
            f32x4 acc = {0.f, 0.f, 0.f, 0.f};
            for (int i = 0; i < cnt; ++i) {
                const f32x4 v = *reinterpret_cast<const f32x4*>(
                    xp + (size_t)s_lst[m][i] * H);
                acc += v;
            }
            const f32x4 r = (acc * mul - bs) * sc;
            *reinterpret_cast<f32x4*>(op + (size_t)m * H) = r;
        }
    }
}

extern "C" void kernel_launch(void* const* d_in, const int* in_sizes, int n_in,
                              void* d_out, int out_size, void* d_ws, size_t ws_size,
                              hipStream_t stream) {
    const float* x         = (const float*)d_in[0];
    const float* std_bias  = (const float*)d_in[1];
    const float* std_scale = (const float*)d_in[2];
    const int*   pos       = (const int*)d_in[3];
    // d_in[4] = image_output_length (scalar) -> 256 for this shape
    float* out = (float*)d_out;

    fused_pool_kernel<<<B * OUT / TPB, NT, 0, stream>>>(x, std_bias, std_scale, pos, out);
}

// Round 7
// 29.343 us; speedup vs baseline: 1.1146x; 1.1146x over previous
//
#include <hip/hip_runtime.h>

// Problem constants (fixed shapes from setup_inputs)
#define B 8
#define S 4096
#define H 1152
#define OUT 256
#define KP 4            // pooling window k = sqrt(S/OUT) = 4
#define CAP 16          // per-segment source rows (k*k = 16)
#define H4 (H / 4)      // 288 float4 per output row
#define NT 576          // threads per block = 2 tokens * H4
#define TPB 8           // tokens per block
#define NI4 (S / 2)     // int4 position-pair entries per batch

typedef float f32x4 __attribute__((ext_vector_type(4)));

// Fully fused: one block = 8 output tokens. Scan batch positions once
// (32 KB, L2-resident), build 8 segment lists in LDS, then 4 gather
// iterations (2 tokens each, one float4 per thread).
// Fast path: hoisted wave-uniform "all lists full" -> branchless body,
// unroll 2 (32 loads in flight, no VGPR spill cliff).
__global__ __launch_bounds__(NT) void fused_pool_kernel(
    const float* __restrict__ x, const float* __restrict__ bias,
    const float* __restrict__ scale, const int* __restrict__ pos,
    float* __restrict__ out) {
    const int blk = blockIdx.x;         // over B*OUT/TPB = 256
    const int tid = threadIdx.x;
    const int b   = blk >> 5;           // 32 blocks per batch
    const int seg_base = (blk * TPB) & 255;

    __shared__ int s_max;
    __shared__ int s_cnt[TPB];
    __shared__ int s_lst[TPB][CAP];

    if (tid == 0) s_max = 0;
    if (tid < TPB) s_cnt[tid] = 0;

    // Pass 1: load this batch's positions (int4 = 2 coords, coalesced).
    int px[8], py[8];
    int mymax = 0;
    #pragma unroll
    for (int j = 0; j < 4; ++j) {
        const int i4 = tid + j * NT;
        if (i4 < NI4) {
            const int4 p = reinterpret_cast<const int4*>(pos)[b * NI4 + i4];
            px[2 * j] = p.x;     py[2 * j] = p.y;
            px[2 * j + 1] = p.z; py[2 * j + 1] = p.w;
            mymax = mymax > p.x ? mymax : p.x;
            mymax = mymax > p.z ? mymax : p.z;
        } else {
            px[2 * j] = -1; py[2 * j] = 0;
            px[2 * j + 1] = -1; py[2 * j + 1] = 0;
        }
    }
    #pragma unroll
    for (int off = 32; off > 0; off >>= 1) {
        const int o = __shfl_down(mymax, off, 64);
        mymax = mymax > o ? mymax : o;
    }
    __syncthreads();                    // s_max/s_cnt init visible
    if ((tid & 63) == 0) atomicMax(&s_max, mymax);
    __syncthreads();
    const int mxk = (s_max + 1) / KP;

    // Pass 2: match positions against this block's 8 segments -> LDS lists.
    #pragma unroll
    for (int j = 0; j < 8; ++j) {
        if (px[j] >= 0) {
            const int seg = px[j] / KP + mxk * (py[j] / KP);
            const unsigned m = (unsigned)(seg - seg_base);
            if (m < (unsigned)TPB) {
                const int slot = atomicAdd(&s_cnt[m], 1);
                if (slot < CAP)
                    s_lst[m][slot] = 2 * (tid + (j >> 1) * NT) + (j & 1);
            }
        }
    }
    __syncthreads();

    // Gather + pool + affine: 4 iterations, one float4 per thread each.
    const int k  = tid >= H4 ? 1 : 0;
    const int h4 = tid - k * H4;
    const float* xp = x + (size_t)b * S * H + (size_t)h4 * 4;
    const float mul = sqrtf((float)H) * (1.0f / (KP * KP));
    const f32x4 bs = *reinterpret_cast<const f32x4*>(bias + h4 * 4);
    const f32x4 sc = *reinterpret_cast<const f32x4*>(scale + h4 * 4);
    float* op = out + (size_t)blk * TPB * H + (size_t)h4 * 4;

    // Wave-uniform: are all 8 lists exactly full? (canonical 4x4 pooling)
    bool fast = true;
    #pragma unroll
    for (int m = 0; m < TPB; ++m) fast = fast && (s_cnt[m] == CAP);

    if (fast) {
        // Branchless body; unroll 2 keeps <=32 loads in flight (no spill).
        #pragma unroll 2
        for (int p = 0; p < TPB / 2; ++p) {
            const int m = 2 * p + k;
            f32x4 acc = {0.f, 0.f, 0.f, 0.f};
            #pragma unroll
            for (int i = 0; i < CAP; ++i) {
                const f32x4 v = *reinterpret_cast<const f32x4*>(
                    xp + (size_t)s_lst[m][i] * H);
                acc += v;
            }
            const f32x4 r = (acc * mul - bs) * sc;
            __builtin_nontemporal_store(
                r, reinterpret_cast<f32x4*>(op + (size_t)m * H));
        }
    } else {
        for (int p = 0; p < TPB / 2; ++p) {
            const int m = 2 * p + k;
            int cnt = s_cnt[m];
            if (cnt > CAP) cnt = CAP;
            f32x4 acc = {0.f, 0.f, 0.f, 0.f};
            for (int i = 0; i < cnt; ++i) {
                const f32x4 v = *reinterpret_cast<const f32x4*>(
                    xp + (size_t)s_lst[m][i] * H);
                acc += v;
            }
            const f32x4 r = (acc * mul - bs) * sc;
            *reinterpret_cast<f32x4*>(op + (size_t)m * H) = r;
        }
    }
}

extern "C" void kernel_launch(void* const* d_in, const int* in_sizes, int n_in,
                              void* d_out, int out_size, void* d_ws, size_t ws_size,
                              hipStream_t stream) {
    const float* x         = (const float*)d_in[0];
    const float* std_bias  = (const float*)d_in[1];
    const float* std_scale = (const float*)d_in[2];
    const int*   pos       = (const int*)d_in[3];
    // d_in[4] = image_output_length (scalar) -> 256 for this shape
    float* out = (float*)d_out;

    fused_pool_kernel<<<B * OUT / TPB, NT, 0, stream>>>(x, std_bias, std_scale, pos, out);
}